// Round 11
// baseline (335.804 us; speedup 1.0000x reference)
//
#include <hip/hip_runtime.h>

#define NROWS 262144   // 256*32*32
#define DDIM  64
#define KCODE 1024
#define GATHER_BLOCKS ((NROWS * 16) / 256)   // 16384
// Packed-filter flag window: must cover 2*(certified approx err 1.6e-3 +
// mantissa-pack truncation <=2e-3 at |sv_b|<=32) = 7.2e-3. Conservative: 8e-3.
#define WINDOWP 8e-3f
#define SVBIAS  16.0f   // |norm - 2dot| <= 11.5 worst-case -> sv_b in [4.5, 27.5]

// ---- ws layout (bytes) ----
// [0)        eT       float[KCODE*DDIM]   = 262144 B  (codebook transposed, [k][d])
// [262144)   norms    float[KCODE]        = 4096 B    (numpy-order sum of squares)
// [266240)   ph       ushort[32*4*64*8]   = 131072 B  (bf16 hi, 32x32-fragment-packed)
// [397312)   pl       ushort[32*4*64*8]   = 131072 B  (bf16 lo, 32x32-fragment-packed)
// [528384)   idx      int[NROWS]          = 1 MiB     (bit31 = needs exact rescore)
// [1576960)  partials double[16384]       = 128 KiB
// [1708032)  cnt      int                 (compact-list counter, zeroed by vq_prep)
// [1709056)  list     int[NROWS]          = 1 MiB     (compacted flagged-row worklist)
//
// Fragment pack (32x32x16): ph/pl[((tile*4+kstep)<<9) + lane*8 + j] holds bf16
// hi/lo of dim d = kstep*16 + (lane>>5)*8 + j of code k = tile*32 + (lane&31) —
// the exact B lane-fragment of mfma_f32_32x32x16_bf16 (C layout HW-verified
// m74/m101). Loads are 64 lanes x contiguous 16 B.
//
// ROUND-11 (BUGFIX of r10): r10 FAILED absmax=0.1 — the mantissa pack OR'd the
// code into sv's low 10 bits WITHOUT CLEARING them (`bits(sv)|code`), so the
// extracted code was sv_low10|code = garbage on unflagged rows (0.1 = 2*max|e|
// = wrong-codebook-row signature; flagged rows were rescored, bounding the
// error). Fix: p = float((bits(sv) & ~0x3FF) | code) — one v_and_or_b32.
// The truncation (round-down <=1024 ulp <= 2e-3) is exactly what WINDOWP
// already budgeted. Masked-tie -> smaller code wins; any row where that could
// differ from exact first-index argmin is inside the window -> flagged ->
// exact rescore. All else byte-identical to r10.
//
// ROUND-10 RATIONALE (counter-derived, unchanged): r9 NEUTRAL at 145us with
// VGPR_Count=68 << ~128 needed -> (m1,m2,id) tracker parked in AGPRs;
// VALUBusy back-solve gives ~290 VALU ops/tile vs ~120 source ops — delta is
// accvgpr_read/write shuffling. CODE-IN-MANTISSA kills the id[] array (16
// regs) + cmp/cndmask; merge 7->4 ops/level. Flag rate ~2x (~8%) — rescore_b
// is cheap, off top-5. Tripwires: VGPR > 128 or WRITE_SIZE >> 2 MB = spill.
//
// SEMANTICS (exact path verified bit-exact through r9, absmax 0.0): oracle =
// numpy fp32, AVX512 pairwise sumsq, sequential-d fp32-FMA dot,
// dist = fl(fl(sumx+norm)-2dot), first-index argmin, out = fl(x + fl(q-x)).
// Exact path preserved in vq_prep / vq_rescore* / vq_gather. vq_filter is
// APPROXIMATE with a conservative flag window; near-ties/noise-affected rows
// are rescored exactly.
//
// HISTORY (counter-verified):
//  rescore: r0 305us latency -> r1 spill 626us BAD -> r2 348us serialized
//           -> r3 vq_rescore_b block-per-4-rows: off top-5 (<40us). GOOD.
//  filter:  r3 253us divergent-B -> r4 166us fragment-packed -> r5 167us LDS
//           staging NEUTRAL -> r6 146us 32x32 MFMA -> r7 staging SPILL 343us
//           -> r8 acc-init refold REGRESSED 165us -> r9 sw-pipeline NEUTRAL
//           145us (tracker in AGPRs) -> r10 mantissa-pack FAILED (no clear
//           before OR).

typedef short bf16x8 __attribute__((ext_vector_type(8)));
typedef float f32x4  __attribute__((ext_vector_type(4)));
typedef float f32x16 __attribute__((ext_vector_type(16)));

__device__ __forceinline__ unsigned short bf16_rne(float f) {
    unsigned u = __float_as_uint(f);
    unsigned r = u + 0x7fffu + ((u >> 16) & 1u);
    return (unsigned short)(r >> 16);
}

// ------------------------------------------------------------------
// P: transpose codebook, numpy-order norms, 32x32-fragment-packed bf16 hi/lo,
// zero worklist cnt (r6/r9 version, verbatim)
__global__ __launch_bounds__(256) void vq_prep(const float* __restrict__ e,
                                               float* __restrict__ eT,
                                               float* __restrict__ norms,
                                               unsigned short* __restrict__ ph,
                                               unsigned short* __restrict__ pl,
                                               int* cnt) {
#pragma clang fp contract(off)
    if (cnt && blockIdx.x == 0 && threadIdx.x == 0) *cnt = 0;
    const int k = blockIdx.x * 256 + threadIdx.x;   // 4 blocks x 256 = 1024
    const int tile = k >> 5;          // 32 codes per 32x32 tile
    const int col  = k & 31;
    float acc = 0.0f;
    for (int d = 0; d < DDIM; ++d) {
        float v = e[d * KCODE + k];      // e is [D][K]; coalesced across k-lanes
        eT[(k << 6) + d] = v;
        unsigned short h = bf16_rne(v);
        float hf = __uint_as_float((unsigned)h << 16);
        // B-fragment pack: kstep = d>>4, lane = ((d&15)>>3)*32 + col, j = d&7
        const int kstep = d >> 4;
        const int lane  = (((d & 15) >> 3) << 5) | col;
        const int pidx  = (((tile << 2) + kstep) << 9) + (lane << 3) + (d & 7);
        ph[pidx] = h;
        pl[pidx] = bf16_rne(v - hf);     // Sterbenz: v-hf exact
        float sq = v * v;                // rounded square (numpy elementwise mul)
        acc = acc + sq;                  // sequential adds (numpy axis-0 reduce)
    }
    norms[k] = acc;
}

// ------------------------------------------------------------------
// numpy AVX512 pairwise sum of fl(x_d^2) — exact op order, do not touch
__device__ __forceinline__ float numpy_sumsq(const float* xr) {
#pragma clang fp contract(off)
    float u[16];
#pragma unroll
    for (int j = 0; j < 16; ++j) {
        float p0 = xr[j     ] * xr[j     ];
        float p1 = xr[j + 16] * xr[j + 16];
        float p2 = xr[j + 32] * xr[j + 32];
        float p3 = xr[j + 48] * xr[j + 48];
        u[j] = (p0 + p1) + (p2 + p3);
    }
    float v8[8];
#pragma unroll
    for (int j = 0; j < 8; ++j) v8[j] = u[j] + u[j + 8];
    float w4[4];
#pragma unroll
    for (int j = 0; j < 4; ++j) w4[j] = v8[j] + v8[j + 4];
    float y0 = w4[0] + w4[2];
    float y1 = w4[1] + w4[3];
    return y0 + y1;
}

// ------------------------------------------------------------------
// 1: 32x32x16-MFMA split-bf16 approximate argmin with CODE-IN-MANTISSA
// tracking. Wave = 32 rows x 1024 codes. Per k-tile: 12 MFMAs + 16 packed
// tracker slots (fmaf, and_or, med3, min). B loads software-pipelined (r9).
__global__ __launch_bounds__(256, 4) void vq_filter(const float* __restrict__ x,
                                                    const unsigned short* __restrict__ ph,
                                                    const unsigned short* __restrict__ pl,
                                                    const float* __restrict__ norms,
                                                    int* __restrict__ idx,
                                                    int* cnt,
                                                    int* list) {
    const int lane = threadIdx.x & 63;
    const int wave = threadIdx.x >> 6;
    const int wrow = blockIdx.x * 128 + wave * 32;   // 32 rows per wave
    const int arow = lane & 31;       // A row / C col-class
    const int half = lane >> 5;       // A k-group / C row-half

    // ---- build A fragments (hi/lo), 4 k-steps ----
    // A layout (mirrors verified m120): A[row=lane&31][k=(lane>>5)*8+j]
    bf16x8 ah[4], al[4];
    {
        const float* xp = x + (size_t)(wrow + arow) * DDIM + half * 8;
#pragma unroll
        for (int s = 0; s < 4; ++s) {
            float4 v0 = *(const float4*)(xp + s * 16);
            float4 v1 = *(const float4*)(xp + s * 16 + 4);
            float f[8] = {v0.x, v0.y, v0.z, v0.w, v1.x, v1.y, v1.z, v1.w};
#pragma unroll
            for (int j = 0; j < 8; ++j) {
                unsigned short h = bf16_rne(f[j]);
                float hf = __uint_as_float((unsigned)h << 16);
                ah[s][j] = (short)h;
                al[s][j] = (short)bf16_rne(f[j] - hf);
            }
        }
    }

    // ---- per-lane running packed (min1, min2), 16 slots (C rows) ----
    // low 10 mantissa bits of m1 carry the argmin code.
    float m1[16], m2[16];
#pragma unroll
    for (int r = 0; r < 16; ++r) { m1[r] = 3.4e38f; m2[r] = 3.4e38f; }

    const bf16x8* __restrict__ phv = (const bf16x8*)ph;
    const bf16x8* __restrict__ plv = (const bf16x8*)pl;

    // fragment index (bf16x8 units): (tile<<8) + (kstep<<6) + lane
    // ---- prologue: prefetch k0/k1 of tile 0 ----
    bf16x8 bh0 = phv[lane];
    bf16x8 bh1 = phv[64 + lane];
    bf16x8 bl0 = plv[lane];
    bf16x8 bl1 = plv[64 + lane];

    for (int tile = 0; tile < KCODE / 32; ++tile) {
        const int base = tile << 8;
        // issue k2/k3 loads of CURRENT tile; latency hides under k0/k1 MFMAs
        bf16x8 bh2 = phv[base + 128 + lane];
        bf16x8 bh3 = phv[base + 192 + lane];
        bf16x8 bl2 = plv[base + 128 + lane];
        bf16x8 bl3 = plv[base + 192 + lane];

        const int code = (tile << 5) | arow;          // this lane's C col
        const float nrm4 = norms[code] + SVBIAS;      // feeds epilogue only

        f32x16 acc = {0.f,0.f,0.f,0.f,0.f,0.f,0.f,0.f,
                      0.f,0.f,0.f,0.f,0.f,0.f,0.f,0.f};
        acc = __builtin_amdgcn_mfma_f32_32x32x16_bf16(ah[0], bh0, acc, 0, 0, 0);
        acc = __builtin_amdgcn_mfma_f32_32x32x16_bf16(ah[0], bl0, acc, 0, 0, 0);
        acc = __builtin_amdgcn_mfma_f32_32x32x16_bf16(al[0], bh0, acc, 0, 0, 0);
        acc = __builtin_amdgcn_mfma_f32_32x32x16_bf16(ah[1], bh1, acc, 0, 0, 0);
        acc = __builtin_amdgcn_mfma_f32_32x32x16_bf16(ah[1], bl1, acc, 0, 0, 0);
        acc = __builtin_amdgcn_mfma_f32_32x32x16_bf16(al[1], bh1, acc, 0, 0, 0);

        // ---- prefetch k0/k1 of NEXT tile while k2/k3 MFMAs run ----
        if (tile + 1 < KCODE / 32) {
            const int nb = base + 256;
            bh0 = phv[nb + lane];
            bh1 = phv[nb + 64 + lane];
            bl0 = plv[nb + lane];
            bl1 = plv[nb + 64 + lane];
        }

        acc = __builtin_amdgcn_mfma_f32_32x32x16_bf16(ah[2], bh2, acc, 0, 0, 0);
        acc = __builtin_amdgcn_mfma_f32_32x32x16_bf16(ah[2], bl2, acc, 0, 0, 0);
        acc = __builtin_amdgcn_mfma_f32_32x32x16_bf16(al[2], bh2, acc, 0, 0, 0);
        acc = __builtin_amdgcn_mfma_f32_32x32x16_bf16(ah[3], bh3, acc, 0, 0, 0);
        acc = __builtin_amdgcn_mfma_f32_32x32x16_bf16(ah[3], bl3, acc, 0, 0, 0);
        acc = __builtin_amdgcn_mfma_f32_32x32x16_bf16(al[3], bh3, acc, 0, 0, 0);

        // C layout (verified m74/m101): col=lane&31, row=(r&3)+8*(r>>2)+4*half
        // packed tracker: clear low 10 bits THEN insert code (v_and_or_b32).
#pragma unroll
        for (int r = 0; r < 16; ++r) {
            float sv = fmaf(-2.0f, acc[r], nrm4);    // biased score, >0
            float p  = __uint_as_float((__float_as_uint(sv) & ~0x3FFu)
                                       | (unsigned)code);
            m2[r] = __builtin_amdgcn_fmed3f(m1[r], m2[r], p);
            m1[r] = fminf(m1[r], p);
        }
    }

    // ---- cross-lane merge over the 32 code-columns (within each 32-lane half)
#pragma unroll
    for (int r = 0; r < 16; ++r) {
        float a1 = m1[r], a2 = m2[r];
        for (int mask = 1; mask < 32; mask <<= 1) {
            float o1 = __shfl_xor(a1, mask, 64);
            float o2 = __shfl_xor(a2, mask, 64);
            a2 = fminf(fminf(a2, o2), fmaxf(a1, o1));
            a1 = fminf(a1, o1);
        }
        m1[r] = a1; m2[r] = a2;
    }

    // After the merge, (m1,m2) are uniform across each 32-lane half, so
    // every lane computes its half's flag count (no divergence).
    int nf = 0;
#pragma unroll
    for (int r = 0; r < 16; ++r) {
        float m1v = __uint_as_float(__float_as_uint(m1[r]) & ~0x3FFu);
        float m2v = __uint_as_float(__float_as_uint(m2[r]) & ~0x3FFu);
        nf += ((m2v - m1v) <= WINDOWP) ? 1 : 0;
    }

    // wave-aggregated worklist append: ONE atomic per wave
    int myoff = 0;
    if (list) {
        int nf0 = __shfl(nf, 0, 64);
        int nf1 = __shfl(nf, 32, 64);
        int wtotal = nf0 + nf1;
        int wbase = 0;
        if (lane == 0 && wtotal) wbase = atomicAdd(cnt, wtotal);
        wbase = __shfl(wbase, 0, 64);
        myoff = wbase + (half ? nf0 : 0);
    }

    if (arow == 0) {   // lanes 0 (half=0 rows) and 32 (half=1 rows) write
#pragma unroll
        for (int r = 0; r < 16; ++r) {
            int row = wrow + (r & 3) + 8 * (r >> 2) + 4 * half;
            unsigned mu = __float_as_uint(m1[r]);
            int code_out = (int)(mu & 0x3FFu);       // valid: field was cleared
            float m1v = __uint_as_float(mu & ~0x3FFu);
            float m2v = __uint_as_float(__float_as_uint(m2[r]) & ~0x3FFu);
            bool flag = (m2v - m1v) <= WINDOWP;
            idx[row] = flag ? (code_out | 0x80000000) : code_out;
            if (list && flag) list[myoff++] = row;
        }
    }
}

// ------------------------------------------------------------------
// Rb: exact numpy rescore, one BLOCK per group of 4 worklist rows.
// Thread t owns codes k = 4t..4t+3 (ascending within thread; lexicographic
// (value,index) reduction across threads => global first-index argmin).
// Per d-step: one dwordx4 load of e[d][4t..4t+3] (wave reads a contiguous
// 1 KiB slice -> fully coalesced) + LDS broadcast of xs[r][d] + 16 chained
// FMAs (4 rows x 4 codes, independent chains -> issue-bound, latency hidden).
// Each chain's op order is IDENTICAL to vq_rescore: bit-exact.
__global__ __launch_bounds__(256) void vq_rescore_b(const float* __restrict__ x,
                                                    const float* __restrict__ e,   // [D][K]
                                                    const float* __restrict__ norms,
                                                    int* __restrict__ idx,
                                                    const int* __restrict__ cnt,
                                                    const int* __restrict__ list) {
#pragma clang fp contract(off)
    __shared__ float xs[4][DDIM];     // 4 staged rows
    __shared__ float sumxs[4];
    __shared__ int   rows_s[4];
    __shared__ float wval[4][4];      // [row][wave] lex-reduce partials
    __shared__ int   widx[4][4];

    const int tid  = threadIdx.x;
    const int lane = tid & 63;
    const int wave = tid >> 6;
    const int total = *cnt;
    const int ngroups = (total + 3) >> 2;

    const float* ep = e + (tid << 2);                       // e[0][4t]
    const float4 nv = *(const float4*)(norms + (tid << 2)); // norms[4t..4t+3]

    for (int g = blockIdx.x; g < ngroups; g += gridDim.x) {
        const int base = g * 4;
        const int nr = min(4, total - base);

        // ---- stage 4 rows into LDS (64 threads per row, stride-1: no conflicts)
        {
            int r = wave;            // tid>>6: one wave per row
            int d = lane;
            int row = (r < nr) ? list[base + r] : list[base];  // pad with row 0
            if (d == 0) rows_s[r] = row;
            xs[r][d] = x[(size_t)row * DDIM + d];
        }
        __syncthreads();

        // ---- sumsq per row: wave r computes row r with a bit-exact 16-lane tree.
        // u[j] on lane j (j<16); each xor level adds self+other, reproducing
        // numpy's pairwise order exactly (IEEE add is bitwise commutative).
        {
            int r = wave;
            float uj = 0.f;
            if (lane < 16) {
                float a0 = xs[r][lane];
                float a1 = xs[r][lane + 16];
                float a2 = xs[r][lane + 32];
                float a3 = xs[r][lane + 48];
                float p0 = a0 * a0, p1 = a1 * a1, p2 = a2 * a2, p3 = a3 * a3;
                uj = (p0 + p1) + (p2 + p3);
            }
            uj = uj + __shfl_xor(uj, 8, 64);   // v8[j] = u[j] + u[j+8]
            uj = uj + __shfl_xor(uj, 4, 64);   // w4[j] = v8[j] + v8[j+4]
            uj = uj + __shfl_xor(uj, 2, 64);   // y0 = w4[0]+w4[2] (lane0)
            uj = uj + __shfl_xor(uj, 1, 64);   // y0+y1 (lane0)
            if (lane == 0) sumxs[r] = uj;
        }
        __syncthreads();

        // ---- 16 independent sequential-d chains: 4 rows x 4 codes ----
        f32x4 a0 = {0.f, 0.f, 0.f, 0.f};
        f32x4 a1 = {0.f, 0.f, 0.f, 0.f};
        f32x4 a2 = {0.f, 0.f, 0.f, 0.f};
        f32x4 a3 = {0.f, 0.f, 0.f, 0.f};
#pragma unroll 8
        for (int d = 0; d < DDIM; ++d) {
            float4 ev = *(const float4*)(ep + (size_t)d * KCODE);
            float x0 = xs[0][d], x1 = xs[1][d], x2 = xs[2][d], x3 = xs[3][d];
            a0.x = fmaf(x0, ev.x, a0.x); a0.y = fmaf(x0, ev.y, a0.y);
            a0.z = fmaf(x0, ev.z, a0.z); a0.w = fmaf(x0, ev.w, a0.w);
            a1.x = fmaf(x1, ev.x, a1.x); a1.y = fmaf(x1, ev.y, a1.y);
            a1.z = fmaf(x1, ev.z, a1.z); a1.w = fmaf(x1, ev.w, a1.w);
            a2.x = fmaf(x2, ev.x, a2.x); a2.y = fmaf(x2, ev.y, a2.y);
            a2.z = fmaf(x2, ev.z, a2.z); a2.w = fmaf(x2, ev.w, a2.w);
            a3.x = fmaf(x3, ev.x, a3.x); a3.y = fmaf(x3, ev.y, a3.y);
            a3.z = fmaf(x3, ev.z, a3.z); a3.w = fmaf(x3, ev.w, a3.w);
        }

        // ---- per-row distances + lexicographic first-index argmin ----
#pragma unroll
        for (int r = 0; r < 4; ++r) {
            f32x4 ar = (r == 0) ? a0 : (r == 1) ? a1 : (r == 2) ? a2 : a3;
            float sx = sumxs[r];
            float bv = 3.4e38f; int bx = 0;
            {   // ascending k within thread: first-index on ties via strict <
                float t0 = sx + nv.x; float d0 = t0 - 2.0f * ar.x;
                if (d0 < bv) { bv = d0; bx = (tid << 2) + 0; }
                float t1 = sx + nv.y; float d1 = t1 - 2.0f * ar.y;
                if (d1 < bv) { bv = d1; bx = (tid << 2) + 1; }
                float t2 = sx + nv.z; float d2 = t2 - 2.0f * ar.z;
                if (d2 < bv) { bv = d2; bx = (tid << 2) + 2; }
                float t3 = sx + nv.w; float d3 = t3 - 2.0f * ar.w;
                if (d3 < bv) { bv = d3; bx = (tid << 2) + 3; }
            }
            for (int mask = 32; mask; mask >>= 1) {
                float ov = __shfl_xor(bv, mask, 64);
                int   ox = __shfl_xor(bx, mask, 64);
                if (ov < bv || (ov == bv && ox < bx)) { bv = ov; bx = ox; }
            }
            if (lane == 0) { wval[r][wave] = bv; widx[r][wave] = bx; }
        }
        __syncthreads();

        if (tid < nr) {
            float bv = wval[tid][0]; int bx = widx[tid][0];
#pragma unroll
            for (int w = 1; w < 4; ++w) {
                float ov = wval[tid][w]; int ox = widx[tid][w];
                if (ov < bv || (ov == bv && ox < bx)) { bv = ov; bx = ox; }
            }
            idx[rows_s[tid]] = bx;    // clears flag bit
        }
        __syncthreads();   // protect xs/rows_s/wval before next group
    }
}

// ------------------------------------------------------------------
// R (fallback, only if ws too small for the worklist): exact numpy rescore
// of flagged rows. One wave per row. UNCHANGED from verified version.
__global__ __launch_bounds__(256) void vq_rescore(const float* __restrict__ x,
                                                  const float* __restrict__ eT,
                                                  const float* __restrict__ norms,
                                                  int* __restrict__ idx) {
#pragma clang fp contract(off)
    const int wave = threadIdx.x >> 6;
    const int lane = threadIdx.x & 63;
    const int rowbase = blockIdx.x * 16 + wave * 4;   // 16384 blocks x 16 rows
    for (int i = 0; i < 4; ++i) {
        const int row = rowbase + i;
        if (idx[row] >= 0) continue;           // uniform branch (broadcast load)
        float xr[DDIM];
        const float4* xv = (const float4*)(x + (size_t)row * DDIM);
#pragma unroll
        for (int t = 0; t < DDIM / 4; ++t) {
            float4 v = xv[t];
            xr[4*t+0] = v.x; xr[4*t+1] = v.y; xr[4*t+2] = v.z; xr[4*t+3] = v.w;
        }
        float sumx = numpy_sumsq(xr);
        float best = 3.4e38f; int bi = 0;
        for (int j = 0; j < 16; ++j) {
            const int k = j * 64 + lane;       // ascending k per lane
            const float* __restrict__ ek = eT + (k << 6);
            float a = 0.f;
#pragma unroll
            for (int d = 0; d < DDIM; ++d)
                a = fmaf(xr[d], ek[d], a);     // strict sequential d-chain
            float t0 = sumx + norms[k];
            float dist = t0 - 2.0f * a;        // fl(fl(sumx+norm) - 2*dot)
            if (dist < best) { best = dist; bi = k; }
        }
        // lexicographic (value, index) min across 64 lanes = first-index argmin
        for (int mask = 32; mask; mask >>= 1) {
            float ov = __shfl_xor(best, mask, 64);
            int   oi = __shfl_xor(bi,   mask, 64);
            if (ov < best || (ov == best && oi < bi)) { best = ov; bi = oi; }
        }
        if (lane == 0) idx[row] = bi;          // clears flag bit
    }
}

// ------------------------------------------------------------------
// 2: gather + straight-through + per-BLOCK loss partial (UNCHANGED, verified)
__global__ __launch_bounds__(256) void vq_gather(const float* __restrict__ x,
                                                 const float* __restrict__ eT,
                                                 const int* __restrict__ idx,
                                                 float* __restrict__ out,
                                                 double* __restrict__ partials) {
#pragma clang fp contract(off)
    __shared__ float wsum[4];
    const int t   = blockIdx.x * 256 + threadIdx.x;   // NROWS*16 threads
    const int row = t >> 4;
    const int j   = t & 15;
    const int k   = idx[row];
    float4 q  = ((const float4*)eT)[(k << 4) + j];
    float4 xv = ((const float4*)x)[t];
    float dx = q.x - xv.x, dy = q.y - xv.y, dz = q.z - xv.z, dw = q.w - xv.w;
    float4 o;
    o.x = xv.x + dx; o.y = xv.y + dy; o.z = xv.z + dz; o.w = xv.w + dw;
    ((float4*)out)[t] = o;
    float s = dx*dx + dy*dy + dz*dz + dw*dw;
#pragma unroll
    for (int off = 32; off > 0; off >>= 1) s += __shfl_down(s, off, 64);
    if ((threadIdx.x & 63) == 0) wsum[threadIdx.x >> 6] = s;
    __syncthreads();
    if (threadIdx.x == 0) {
        double b = (double)wsum[0] + (double)wsum[1]
                 + (double)wsum[2] + (double)wsum[3];
        partials[blockIdx.x] = b;
    }
}

// ------------------------------------------------------------------
// 3: reduce block partials; loss = 1.25 * mse (UNCHANGED, verified)
__global__ __launch_bounds__(256) void vq_finalize(const double* __restrict__ partials,
                                                   float* __restrict__ out_loss) {
    __shared__ double sd[256];
    double a = 0.0;
    for (int i = threadIdx.x; i < GATHER_BLOCKS; i += 256) a += partials[i];
    sd[threadIdx.x] = a;
    __syncthreads();
    for (int s = 128; s > 0; s >>= 1) {
        if (threadIdx.x < s) sd[threadIdx.x] += sd[threadIdx.x + s];
        __syncthreads();
    }
    if (threadIdx.x == 0) {
        double mse = sd[0] / (double)((size_t)NROWS * DDIM);
        *out_loss = (float)(1.25 * mse);
    }
}

// ------------------------------------------------------------------
extern "C" void kernel_launch(void* const* d_in, const int* in_sizes, int n_in,
                              void* d_out, int out_size, void* d_ws, size_t ws_size,
                              hipStream_t stream) {
    const float* x = (const float*)d_in[0];        // [N, 64]
    const float* e = (const float*)d_in[1];        // [64, 1024]
    float* out = (float*)d_out;                    // [N*64 quantized_st] + [1 loss]

    char* ws = (char*)d_ws;
    float*          eT       = (float*)(ws + 0);
    float*          norms    = (float*)(ws + 262144);
    unsigned short* ph       = (unsigned short*)(ws + 266240);
    unsigned short* pl       = (unsigned short*)(ws + 397312);
    int*            idx      = (int*)(ws + 528384);
    double*         partials = (double*)(ws + 1576960);

    const size_t CNT_OFF  = 1708032;
    const size_t LIST_OFF = 1709056;
    const size_t REQUIRED = LIST_OFF + (size_t)NROWS * 4;   // ~2.63 MiB
    const bool compact = (ws_size >= REQUIRED);
    int* cnt  = compact ? (int*)(ws + CNT_OFF)  : (int*)0;
    int* list = compact ? (int*)(ws + LIST_OFF) : (int*)0;

    vq_prep    <<<KCODE / 256,   256, 0, stream>>>(e, eT, norms, ph, pl, cnt);
    vq_filter  <<<NROWS / 128,   256, 0, stream>>>(x, ph, pl, norms, idx, cnt, list);
    if (compact)
        vq_rescore_b<<<2048,     256, 0, stream>>>(x, e, norms, idx, cnt, list);
    else
        vq_rescore  <<<NROWS/16, 256, 0, stream>>>(x, eT, norms, idx);
    vq_gather  <<<GATHER_BLOCKS, 256, 0, stream>>>(x, eT, idx, out, partials);
    vq_finalize<<<1,             256, 0, stream>>>(partials, out + (size_t)NROWS * DDIM);
}

// Round 12
// 333.582 us; speedup vs baseline: 1.0067x; 1.0067x over previous
//
#include <hip/hip_runtime.h>

#define NROWS 262144   // 256*32*32
#define DDIM  64
#define KCODE 1024
#define GATHER_BLOCKS ((NROWS * 16) / 256)   // 16384
// Packed-filter flag window: must cover 2*(certified approx err 1.6e-3 +
// mantissa-pack truncation <=2e-3 at |sv_b|<=32) = 7.2e-3. Conservative: 8e-3.
#define WINDOWP 8e-3f
#define SVBIAS  16.0f   // |norm - 2dot| <= 11.5 worst-case -> sv_b in [4.5, 27.5]

// ---- ws layout (bytes) ----
// [0)        eT       float[KCODE*DDIM]   = 262144 B  (codebook transposed, [k][d])
// [262144)   norms    float[KCODE]        = 4096 B    (numpy-order sum of squares)
// [266240)   ph       ushort[32*4*64*8]   = 131072 B  (bf16 hi, 32x32-fragment-packed)
// [397312)   pl       ushort[32*4*64*8]   = 131072 B  (bf16 lo, 32x32-fragment-packed)
// [528384)   idx      int[NROWS]          = 1 MiB     (bit31 = needs exact rescore)
// [1576960)  partials double[16384]       = 128 KiB
// [1708032)  cnt      int                 (compact-list counter, zeroed by vq_prep)
// [1709056)  list     int[NROWS]          = 1 MiB     (compacted flagged-row worklist)
//
// Fragment pack (32x32x16): ph/pl[((tile*4+kstep)<<9) + lane*8 + j] holds bf16
// hi/lo of dim d = kstep*16 + (lane>>5)*8 + j of code k = tile*32 + (lane&31) —
// the exact B lane-fragment of mfma_f32_32x32x16_bf16 (C layout HW-verified
// m74/m101). Loads are 64 lanes x contiguous 16 B.
//
// ROUND-12 RATIONALE (counter-derived): r11 verified the packed tracker
// (absmax 0.0) but REGRESSED 145->155us with VGPR_Count STILL 64 and VALUBusy
// UP to 47% — launch_bounds(256,4) caps the unified file at 512/4=128/thread,
// so the allocator parks ~64 regs in AGPRs and the HOT tracker pays
// accvgpr_read/write on every med3/min (~160 moves/tile; matches the ~290
// ops/tile back-solve vs ~75 source ops). ONE change: launch_bounds(256,2)
// raises the budget to 256/thread. Needed live state ~130 -> all-VGPR
// allocation, occupancy still ~3 waves/SIMD (floor(512/130)), AGPR shuttle
// gone. SUCCESS SIGNATURE: VGPR_Count ~110-150. FAILURE: stays ~64 ->
// allocator not budget-driven; revert + attack L2 pack traffic instead.
// Tripwires: VGPR > 180 or WRITE_SIZE >> 4 MB.
//
// SEMANTICS (verified r11, absmax 0.0): oracle = numpy fp32, AVX512 pairwise
// sumsq, sequential-d fp32-FMA dot, dist = fl(fl(sumx+norm)-2dot), first-index
// argmin, out = fl(x + fl(q-x)). Exact path preserved in vq_prep /
// vq_rescore* / vq_gather. vq_filter is APPROXIMATE with a conservative flag
// window (WINDOWP covers cert err + pack truncation; masked-tie -> smaller
// code wins; any ambiguous row is flagged and exactly rescored).
//
// HISTORY (counter-verified):
//  rescore: r0 305us latency -> r1 spill 626us BAD -> r2 348us serialized
//           -> r3 vq_rescore_b block-per-4-rows: off top-5 (<40us). GOOD.
//  filter:  r3 253us divergent-B -> r4 166us fragment-packed -> r5 167us LDS
//           staging NEUTRAL -> r6 146us 32x32 MFMA -> r7 staging SPILL 343us
//           -> r8 acc-init refold REGRESSED 165us -> r9 sw-pipeline NEUTRAL
//           145us (tracker in AGPRs) -> r10 pack bug FAILED -> r11 pack fixed,
//           still AGPR-parked (VGPR=64, VALU up): 155us.

typedef short bf16x8 __attribute__((ext_vector_type(8)));
typedef float f32x4  __attribute__((ext_vector_type(4)));
typedef float f32x16 __attribute__((ext_vector_type(16)));

__device__ __forceinline__ unsigned short bf16_rne(float f) {
    unsigned u = __float_as_uint(f);
    unsigned r = u + 0x7fffu + ((u >> 16) & 1u);
    return (unsigned short)(r >> 16);
}

// ------------------------------------------------------------------
// P: transpose codebook, numpy-order norms, 32x32-fragment-packed bf16 hi/lo,
// zero worklist cnt (r6/r9 version, verbatim)
__global__ __launch_bounds__(256) void vq_prep(const float* __restrict__ e,
                                               float* __restrict__ eT,
                                               float* __restrict__ norms,
                                               unsigned short* __restrict__ ph,
                                               unsigned short* __restrict__ pl,
                                               int* cnt) {
#pragma clang fp contract(off)
    if (cnt && blockIdx.x == 0 && threadIdx.x == 0) *cnt = 0;
    const int k = blockIdx.x * 256 + threadIdx.x;   // 4 blocks x 256 = 1024
    const int tile = k >> 5;          // 32 codes per 32x32 tile
    const int col  = k & 31;
    float acc = 0.0f;
    for (int d = 0; d < DDIM; ++d) {
        float v = e[d * KCODE + k];      // e is [D][K]; coalesced across k-lanes
        eT[(k << 6) + d] = v;
        unsigned short h = bf16_rne(v);
        float hf = __uint_as_float((unsigned)h << 16);
        // B-fragment pack: kstep = d>>4, lane = ((d&15)>>3)*32 + col, j = d&7
        const int kstep = d >> 4;
        const int lane  = (((d & 15) >> 3) << 5) | col;
        const int pidx  = (((tile << 2) + kstep) << 9) + (lane << 3) + (d & 7);
        ph[pidx] = h;
        pl[pidx] = bf16_rne(v - hf);     // Sterbenz: v-hf exact
        float sq = v * v;                // rounded square (numpy elementwise mul)
        acc = acc + sq;                  // sequential adds (numpy axis-0 reduce)
    }
    norms[k] = acc;
}

// ------------------------------------------------------------------
// numpy AVX512 pairwise sum of fl(x_d^2) — exact op order, do not touch
__device__ __forceinline__ float numpy_sumsq(const float* xr) {
#pragma clang fp contract(off)
    float u[16];
#pragma unroll
    for (int j = 0; j < 16; ++j) {
        float p0 = xr[j     ] * xr[j     ];
        float p1 = xr[j + 16] * xr[j + 16];
        float p2 = xr[j + 32] * xr[j + 32];
        float p3 = xr[j + 48] * xr[j + 48];
        u[j] = (p0 + p1) + (p2 + p3);
    }
    float v8[8];
#pragma unroll
    for (int j = 0; j < 8; ++j) v8[j] = u[j] + u[j + 8];
    float w4[4];
#pragma unroll
    for (int j = 0; j < 4; ++j) w4[j] = v8[j] + v8[j + 4];
    float y0 = w4[0] + w4[2];
    float y1 = w4[1] + w4[3];
    return y0 + y1;
}

// ------------------------------------------------------------------
// 1: 32x32x16-MFMA split-bf16 approximate argmin with CODE-IN-MANTISSA
// tracking. Wave = 32 rows x 1024 codes. Per k-tile: 12 MFMAs + 16 packed
// tracker slots (fmaf, and_or, med3, min). B loads software-pipelined (r9).
// launch_bounds(256,2): 256-reg/thread budget so the ~130 live regs stay in
// architectural VGPRs (no AGPR shuttle) — see ROUND-12 note.
__global__ __launch_bounds__(256, 2) void vq_filter(const float* __restrict__ x,
                                                    const unsigned short* __restrict__ ph,
                                                    const unsigned short* __restrict__ pl,
                                                    const float* __restrict__ norms,
                                                    int* __restrict__ idx,
                                                    int* cnt,
                                                    int* list) {
    const int lane = threadIdx.x & 63;
    const int wave = threadIdx.x >> 6;
    const int wrow = blockIdx.x * 128 + wave * 32;   // 32 rows per wave
    const int arow = lane & 31;       // A row / C col-class
    const int half = lane >> 5;       // A k-group / C row-half

    // ---- build A fragments (hi/lo), 4 k-steps ----
    // A layout (mirrors verified m120): A[row=lane&31][k=(lane>>5)*8+j]
    bf16x8 ah[4], al[4];
    {
        const float* xp = x + (size_t)(wrow + arow) * DDIM + half * 8;
#pragma unroll
        for (int s = 0; s < 4; ++s) {
            float4 v0 = *(const float4*)(xp + s * 16);
            float4 v1 = *(const float4*)(xp + s * 16 + 4);
            float f[8] = {v0.x, v0.y, v0.z, v0.w, v1.x, v1.y, v1.z, v1.w};
#pragma unroll
            for (int j = 0; j < 8; ++j) {
                unsigned short h = bf16_rne(f[j]);
                float hf = __uint_as_float((unsigned)h << 16);
                ah[s][j] = (short)h;
                al[s][j] = (short)bf16_rne(f[j] - hf);
            }
        }
    }

    // ---- per-lane running packed (min1, min2), 16 slots (C rows) ----
    // low 10 mantissa bits of m1 carry the argmin code.
    float m1[16], m2[16];
#pragma unroll
    for (int r = 0; r < 16; ++r) { m1[r] = 3.4e38f; m2[r] = 3.4e38f; }

    const bf16x8* __restrict__ phv = (const bf16x8*)ph;
    const bf16x8* __restrict__ plv = (const bf16x8*)pl;

    // fragment index (bf16x8 units): (tile<<8) + (kstep<<6) + lane
    // ---- prologue: prefetch k0/k1 of tile 0 ----
    bf16x8 bh0 = phv[lane];
    bf16x8 bh1 = phv[64 + lane];
    bf16x8 bl0 = plv[lane];
    bf16x8 bl1 = plv[64 + lane];

    for (int tile = 0; tile < KCODE / 32; ++tile) {
        const int base = tile << 8;
        // issue k2/k3 loads of CURRENT tile; latency hides under k0/k1 MFMAs
        bf16x8 bh2 = phv[base + 128 + lane];
        bf16x8 bh3 = phv[base + 192 + lane];
        bf16x8 bl2 = plv[base + 128 + lane];
        bf16x8 bl3 = plv[base + 192 + lane];

        const int code = (tile << 5) | arow;          // this lane's C col
        const float nrm4 = norms[code] + SVBIAS;      // feeds epilogue only

        f32x16 acc = {0.f,0.f,0.f,0.f,0.f,0.f,0.f,0.f,
                      0.f,0.f,0.f,0.f,0.f,0.f,0.f,0.f};
        acc = __builtin_amdgcn_mfma_f32_32x32x16_bf16(ah[0], bh0, acc, 0, 0, 0);
        acc = __builtin_amdgcn_mfma_f32_32x32x16_bf16(ah[0], bl0, acc, 0, 0, 0);
        acc = __builtin_amdgcn_mfma_f32_32x32x16_bf16(al[0], bh0, acc, 0, 0, 0);
        acc = __builtin_amdgcn_mfma_f32_32x32x16_bf16(ah[1], bh1, acc, 0, 0, 0);
        acc = __builtin_amdgcn_mfma_f32_32x32x16_bf16(ah[1], bl1, acc, 0, 0, 0);
        acc = __builtin_amdgcn_mfma_f32_32x32x16_bf16(al[1], bh1, acc, 0, 0, 0);

        // ---- prefetch k0/k1 of NEXT tile while k2/k3 MFMAs run ----
        if (tile + 1 < KCODE / 32) {
            const int nb = base + 256;
            bh0 = phv[nb + lane];
            bh1 = phv[nb + 64 + lane];
            bl0 = plv[nb + lane];
            bl1 = plv[nb + 64 + lane];
        }

        acc = __builtin_amdgcn_mfma_f32_32x32x16_bf16(ah[2], bh2, acc, 0, 0, 0);
        acc = __builtin_amdgcn_mfma_f32_32x32x16_bf16(ah[2], bl2, acc, 0, 0, 0);
        acc = __builtin_amdgcn_mfma_f32_32x32x16_bf16(al[2], bh2, acc, 0, 0, 0);
        acc = __builtin_amdgcn_mfma_f32_32x32x16_bf16(ah[3], bh3, acc, 0, 0, 0);
        acc = __builtin_amdgcn_mfma_f32_32x32x16_bf16(ah[3], bl3, acc, 0, 0, 0);
        acc = __builtin_amdgcn_mfma_f32_32x32x16_bf16(al[3], bh3, acc, 0, 0, 0);

        // C layout (verified m74/m101): col=lane&31, row=(r&3)+8*(r>>2)+4*half
        // packed tracker: clear low 10 bits THEN insert code (v_and_or_b32).
#pragma unroll
        for (int r = 0; r < 16; ++r) {
            float sv = fmaf(-2.0f, acc[r], nrm4);    // biased score, >0
            float p  = __uint_as_float((__float_as_uint(sv) & ~0x3FFu)
                                       | (unsigned)code);
            m2[r] = __builtin_amdgcn_fmed3f(m1[r], m2[r], p);
            m1[r] = fminf(m1[r], p);
        }
    }

    // ---- cross-lane merge over the 32 code-columns (within each 32-lane half)
#pragma unroll
    for (int r = 0; r < 16; ++r) {
        float a1 = m1[r], a2 = m2[r];
        for (int mask = 1; mask < 32; mask <<= 1) {
            float o1 = __shfl_xor(a1, mask, 64);
            float o2 = __shfl_xor(a2, mask, 64);
            a2 = fminf(fminf(a2, o2), fmaxf(a1, o1));
            a1 = fminf(a1, o1);
        }
        m1[r] = a1; m2[r] = a2;
    }

    // After the merge, (m1,m2) are uniform across each 32-lane half, so
    // every lane computes its half's flag count (no divergence).
    int nf = 0;
#pragma unroll
    for (int r = 0; r < 16; ++r) {
        float m1v = __uint_as_float(__float_as_uint(m1[r]) & ~0x3FFu);
        float m2v = __uint_as_float(__float_as_uint(m2[r]) & ~0x3FFu);
        nf += ((m2v - m1v) <= WINDOWP) ? 1 : 0;
    }

    // wave-aggregated worklist append: ONE atomic per wave
    int myoff = 0;
    if (list) {
        int nf0 = __shfl(nf, 0, 64);
        int nf1 = __shfl(nf, 32, 64);
        int wtotal = nf0 + nf1;
        int wbase = 0;
        if (lane == 0 && wtotal) wbase = atomicAdd(cnt, wtotal);
        wbase = __shfl(wbase, 0, 64);
        myoff = wbase + (half ? nf0 : 0);
    }

    if (arow == 0) {   // lanes 0 (half=0 rows) and 32 (half=1 rows) write
#pragma unroll
        for (int r = 0; r < 16; ++r) {
            int row = wrow + (r & 3) + 8 * (r >> 2) + 4 * half;
            unsigned mu = __float_as_uint(m1[r]);
            int code_out = (int)(mu & 0x3FFu);       // valid: field was cleared
            float m1v = __uint_as_float(mu & ~0x3FFu);
            float m2v = __uint_as_float(__float_as_uint(m2[r]) & ~0x3FFu);
            bool flag = (m2v - m1v) <= WINDOWP;
            idx[row] = flag ? (code_out | 0x80000000) : code_out;
            if (list && flag) list[myoff++] = row;
        }
    }
}

// ------------------------------------------------------------------
// Rb: exact numpy rescore, one BLOCK per group of 4 worklist rows.
// Thread t owns codes k = 4t..4t+3 (ascending within thread; lexicographic
// (value,index) reduction across threads => global first-index argmin).
// Per d-step: one dwordx4 load of e[d][4t..4t+3] (wave reads a contiguous
// 1 KiB slice -> fully coalesced) + LDS broadcast of xs[r][d] + 16 chained
// FMAs (4 rows x 4 codes, independent chains -> issue-bound, latency hidden).
// Each chain's op order is IDENTICAL to vq_rescore: bit-exact.
__global__ __launch_bounds__(256) void vq_rescore_b(const float* __restrict__ x,
                                                    const float* __restrict__ e,   // [D][K]
                                                    const float* __restrict__ norms,
                                                    int* __restrict__ idx,
                                                    const int* __restrict__ cnt,
                                                    const int* __restrict__ list) {
#pragma clang fp contract(off)
    __shared__ float xs[4][DDIM];     // 4 staged rows
    __shared__ float sumxs[4];
    __shared__ int   rows_s[4];
    __shared__ float wval[4][4];      // [row][wave] lex-reduce partials
    __shared__ int   widx[4][4];

    const int tid  = threadIdx.x;
    const int lane = tid & 63;
    const int wave = tid >> 6;
    const int total = *cnt;
    const int ngroups = (total + 3) >> 2;

    const float* ep = e + (tid << 2);                       // e[0][4t]
    const float4 nv = *(const float4*)(norms + (tid << 2)); // norms[4t..4t+3]

    for (int g = blockIdx.x; g < ngroups; g += gridDim.x) {
        const int base = g * 4;
        const int nr = min(4, total - base);

        // ---- stage 4 rows into LDS (64 threads per row, stride-1: no conflicts)
        {
            int r = wave;            // tid>>6: one wave per row
            int d = lane;
            int row = (r < nr) ? list[base + r] : list[base];  // pad with row 0
            if (d == 0) rows_s[r] = row;
            xs[r][d] = x[(size_t)row * DDIM + d];
        }
        __syncthreads();

        // ---- sumsq per row: wave r computes row r with a bit-exact 16-lane tree.
        // u[j] on lane j (j<16); each xor level adds self+other, reproducing
        // numpy's pairwise order exactly (IEEE add is bitwise commutative).
        {
            int r = wave;
            float uj = 0.f;
            if (lane < 16) {
                float a0 = xs[r][lane];
                float a1 = xs[r][lane + 16];
                float a2 = xs[r][lane + 32];
                float a3 = xs[r][lane + 48];
                float p0 = a0 * a0, p1 = a1 * a1, p2 = a2 * a2, p3 = a3 * a3;
                uj = (p0 + p1) + (p2 + p3);
            }
            uj = uj + __shfl_xor(uj, 8, 64);   // v8[j] = u[j] + u[j+8]
            uj = uj + __shfl_xor(uj, 4, 64);   // w4[j] = v8[j] + v8[j+4]
            uj = uj + __shfl_xor(uj, 2, 64);   // y0 = w4[0]+w4[2] (lane0)
            uj = uj + __shfl_xor(uj, 1, 64);   // y0+y1 (lane0)
            if (lane == 0) sumxs[r] = uj;
        }
        __syncthreads();

        // ---- 16 independent sequential-d chains: 4 rows x 4 codes ----
        f32x4 a0 = {0.f, 0.f, 0.f, 0.f};
        f32x4 a1 = {0.f, 0.f, 0.f, 0.f};
        f32x4 a2 = {0.f, 0.f, 0.f, 0.f};
        f32x4 a3 = {0.f, 0.f, 0.f, 0.f};
#pragma unroll 8
        for (int d = 0; d < DDIM; ++d) {
            float4 ev = *(const float4*)(ep + (size_t)d * KCODE);
            float x0 = xs[0][d], x1 = xs[1][d], x2 = xs[2][d], x3 = xs[3][d];
            a0.x = fmaf(x0, ev.x, a0.x); a0.y = fmaf(x0, ev.y, a0.y);
            a0.z = fmaf(x0, ev.z, a0.z); a0.w = fmaf(x0, ev.w, a0.w);
            a1.x = fmaf(x1, ev.x, a1.x); a1.y = fmaf(x1, ev.y, a1.y);
            a1.z = fmaf(x1, ev.z, a1.z); a1.w = fmaf(x1, ev.w, a1.w);
            a2.x = fmaf(x2, ev.x, a2.x); a2.y = fmaf(x2, ev.y, a2.y);
            a2.z = fmaf(x2, ev.z, a2.z); a2.w = fmaf(x2, ev.w, a2.w);
            a3.x = fmaf(x3, ev.x, a3.x); a3.y = fmaf(x3, ev.y, a3.y);
            a3.z = fmaf(x3, ev.z, a3.z); a3.w = fmaf(x3, ev.w, a3.w);
        }

        // ---- per-row distances + lexicographic first-index argmin ----
#pragma unroll
        for (int r = 0; r < 4; ++r) {
            f32x4 ar = (r == 0) ? a0 : (r == 1) ? a1 : (r == 2) ? a2 : a3;
            float sx = sumxs[r];
            float bv = 3.4e38f; int bx = 0;
            {   // ascending k within thread: first-index on ties via strict <
                float t0 = sx + nv.x; float d0 = t0 - 2.0f * ar.x;
                if (d0 < bv) { bv = d0; bx = (tid << 2) + 0; }
                float t1 = sx + nv.y; float d1 = t1 - 2.0f * ar.y;
                if (d1 < bv) { bv = d1; bx = (tid << 2) + 1; }
                float t2 = sx + nv.z; float d2 = t2 - 2.0f * ar.z;
                if (d2 < bv) { bv = d2; bx = (tid << 2) + 2; }
                float t3 = sx + nv.w; float d3 = t3 - 2.0f * ar.w;
                if (d3 < bv) { bv = d3; bx = (tid << 2) + 3; }
            }
            for (int mask = 32; mask; mask >>= 1) {
                float ov = __shfl_xor(bv, mask, 64);
                int   ox = __shfl_xor(bx, mask, 64);
                if (ov < bv || (ov == bv && ox < bx)) { bv = ov; bx = ox; }
            }
            if (lane == 0) { wval[r][wave] = bv; widx[r][wave] = bx; }
        }
        __syncthreads();

        if (tid < nr) {
            float bv = wval[tid][0]; int bx = widx[tid][0];
#pragma unroll
            for (int w = 1; w < 4; ++w) {
                float ov = wval[tid][w]; int ox = widx[tid][w];
                if (ov < bv || (ov == bv && ox < bx)) { bv = ov; bx = ox; }
            }
            idx[rows_s[tid]] = bx;    // clears flag bit
        }
        __syncthreads();   // protect xs/rows_s/wval before next group
    }
}

// ------------------------------------------------------------------
// R (fallback, only if ws too small for the worklist): exact numpy rescore
// of flagged rows. One wave per row. UNCHANGED from verified version.
__global__ __launch_bounds__(256) void vq_rescore(const float* __restrict__ x,
                                                  const float* __restrict__ eT,
                                                  const float* __restrict__ norms,
                                                  int* __restrict__ idx) {
#pragma clang fp contract(off)
    const int wave = threadIdx.x >> 6;
    const int lane = threadIdx.x & 63;
    const int rowbase = blockIdx.x * 16 + wave * 4;   // 16384 blocks x 16 rows
    for (int i = 0; i < 4; ++i) {
        const int row = rowbase + i;
        if (idx[row] >= 0) continue;           // uniform branch (broadcast load)
        float xr[DDIM];
        const float4* xv = (const float4*)(x + (size_t)row * DDIM);
#pragma unroll
        for (int t = 0; t < DDIM / 4; ++t) {
            float4 v = xv[t];
            xr[4*t+0] = v.x; xr[4*t+1] = v.y; xr[4*t+2] = v.z; xr[4*t+3] = v.w;
        }
        float sumx = numpy_sumsq(xr);
        float best = 3.4e38f; int bi = 0;
        for (int j = 0; j < 16; ++j) {
            const int k = j * 64 + lane;       // ascending k per lane
            const float* __restrict__ ek = eT + (k << 6);
            float a = 0.f;
#pragma unroll
            for (int d = 0; d < DDIM; ++d)
                a = fmaf(xr[d], ek[d], a);     // strict sequential d-chain
            float t0 = sumx + norms[k];
            float dist = t0 - 2.0f * a;        // fl(fl(sumx+norm) - 2*dot)
            if (dist < best) { best = dist; bi = k; }
        }
        // lexicographic (value, index) min across 64 lanes = first-index argmin
        for (int mask = 32; mask; mask >>= 1) {
            float ov = __shfl_xor(best, mask, 64);
            int   oi = __shfl_xor(bi,   mask, 64);
            if (ov < best || (ov == best && oi < bi)) { best = ov; bi = oi; }
        }
        if (lane == 0) idx[row] = bi;          // clears flag bit
    }
}

// ------------------------------------------------------------------
// 2: gather + straight-through + per-BLOCK loss partial (UNCHANGED, verified)
__global__ __launch_bounds__(256) void vq_gather(const float* __restrict__ x,
                                                 const float* __restrict__ eT,
                                                 const int* __restrict__ idx,
                                                 float* __restrict__ out,
                                                 double* __restrict__ partials) {
#pragma clang fp contract(off)
    __shared__ float wsum[4];
    const int t   = blockIdx.x * 256 + threadIdx.x;   // NROWS*16 threads
    const int row = t >> 4;
    const int j   = t & 15;
    const int k   = idx[row];
    float4 q  = ((const float4*)eT)[(k << 4) + j];
    float4 xv = ((const float4*)x)[t];
    float dx = q.x - xv.x, dy = q.y - xv.y, dz = q.z - xv.z, dw = q.w - xv.w;
    float4 o;
    o.x = xv.x + dx; o.y = xv.y + dy; o.z = xv.z + dz; o.w = xv.w + dw;
    ((float4*)out)[t] = o;
    float s = dx*dx + dy*dy + dz*dz + dw*dw;
#pragma unroll
    for (int off = 32; off > 0; off >>= 1) s += __shfl_down(s, off, 64);
    if ((threadIdx.x & 63) == 0) wsum[threadIdx.x >> 6] = s;
    __syncthreads();
    if (threadIdx.x == 0) {
        double b = (double)wsum[0] + (double)wsum[1]
                 + (double)wsum[2] + (double)wsum[3];
        partials[blockIdx.x] = b;
    }
}

// ------------------------------------------------------------------
// 3: reduce block partials; loss = 1.25 * mse (UNCHANGED, verified)
__global__ __launch_bounds__(256) void vq_finalize(const double* __restrict__ partials,
                                                   float* __restrict__ out_loss) {
    __shared__ double sd[256];
    double a = 0.0;
    for (int i = threadIdx.x; i < GATHER_BLOCKS; i += 256) a += partials[i];
    sd[threadIdx.x] = a;
    __syncthreads();
    for (int s = 128; s > 0; s >>= 1) {
        if (threadIdx.x < s) sd[threadIdx.x] += sd[threadIdx.x + s];
        __syncthreads();
    }
    if (threadIdx.x == 0) {
        double mse = sd[0] / (double)((size_t)NROWS * DDIM);
        *out_loss = (float)(1.25 * mse);
    }
}

// ------------------------------------------------------------------
extern "C" void kernel_launch(void* const* d_in, const int* in_sizes, int n_in,
                              void* d_out, int out_size, void* d_ws, size_t ws_size,
                              hipStream_t stream) {
    const float* x = (const float*)d_in[0];        // [N, 64]
    const float* e = (const float*)d_in[1];        // [64, 1024]
    float* out = (float*)d_out;                    // [N*64 quantized_st] + [1 loss]

    char* ws = (char*)d_ws;
    float*          eT       = (float*)(ws + 0);
    float*          norms    = (float*)(ws + 262144);
    unsigned short* ph       = (unsigned short*)(ws + 266240);
    unsigned short* pl       = (unsigned short*)(ws + 397312);
    int*            idx      = (int*)(ws + 528384);
    double*         partials = (double*)(ws + 1576960);

    const size_t CNT_OFF  = 1708032;
    const size_t LIST_OFF = 1709056;
    const size_t REQUIRED = LIST_OFF + (size_t)NROWS * 4;   // ~2.63 MiB
    const bool compact = (ws_size >= REQUIRED);
    int* cnt  = compact ? (int*)(ws + CNT_OFF)  : (int*)0;
    int* list = compact ? (int*)(ws + LIST_OFF) : (int*)0;

    vq_prep    <<<KCODE / 256,   256, 0, stream>>>(e, eT, norms, ph, pl, cnt);
    vq_filter  <<<NROWS / 128,   256, 0, stream>>>(x, ph, pl, norms, idx, cnt, list);
    if (compact)
        vq_rescore_b<<<2048,     256, 0, stream>>>(x, e, norms, idx, cnt, list);
    else
        vq_rescore  <<<NROWS/16, 256, 0, stream>>>(x, eT, norms, idx);
    vq_gather  <<<GATHER_BLOCKS, 256, 0, stream>>>(x, eT, idx, out, partials);
    vq_finalize<<<1,             256, 0, stream>>>(partials, out + (size_t)NROWS * DDIM);
}